// Round 2
// baseline (138.723 us; speedup 1.0000x reference)
//
#include <hip/hip_runtime.h>
#include <math.h>

#define ZZ 128
#define CC 12
#define HH 512
#define NB 4096

typedef __attribute__((ext_vector_type(8))) short short8;
typedef __attribute__((ext_vector_type(4))) float f32x4;

__device__ __forceinline__ unsigned short f2bf(float x) {
    unsigned u = __builtin_bit_cast(unsigned, x);
    u += 0x7FFFu + ((u >> 16) & 1u);
    return (unsigned short)(u >> 16);
}
__device__ __forceinline__ float bf2f(unsigned short h) {
    unsigned u = ((unsigned)h) << 16;
    return __builtin_bit_cast(float, u);
}

// ---------------------------------------------------------------------------
// Prep: W1t/W2t transpose + bf16 hi/lo split; edge weights M; out[0:NB] = bf.
// ---------------------------------------------------------------------------
__global__ __launch_bounds__(256) void k_prep(const float* __restrict__ W1,
                                              const float* __restrict__ W2,
                                              const int* __restrict__ adj,
                                              const int* __restrict__ tt,
                                              const float* __restrict__ w0p,
                                              const float* __restrict__ bfp,
                                              short* __restrict__ W1tH, short* __restrict__ W1tL,
                                              short* __restrict__ W2tH, short* __restrict__ W2tL,
                                              float* __restrict__ M, float* __restrict__ outv) {
    int bid = blockIdx.x, t = threadIdx.x;
    if (bid < 80) {
        __shared__ float T[64][65];
        const float* src; short *dH, *dL; int k0, n0, Krows;
        if (bid < 64) { src = W2; dH = W2tH; dL = W2tL; Krows = HH; k0 = (bid & 7) * 64; n0 = (bid >> 3) * 64; }
        else { int b = bid - 64; src = W1; dH = W1tH; dL = W1tL; Krows = ZZ; k0 = (b & 1) * 64; n0 = (b >> 1) * 64; }
#pragma unroll
        for (int it = 0; it < 16; ++it) {
            int idx = t + it * 256; int r = idx >> 6, c = idx & 63;
            T[r][c] = src[(size_t)(k0 + r) * HH + n0 + c];
        }
        __syncthreads();
#pragma unroll
        for (int it = 0; it < 16; ++it) {
            int idx = t + it * 256; int nl = idx >> 6, kl = idx & 63;
            float v = T[kl][nl];
            unsigned short h = f2bf(v);
            float lo = v - bf2f(h);
            size_t o = (size_t)(n0 + nl) * Krows + k0 + kl;
            dH[o] = (short)h; dL[o] = (short)f2bf(lo);
        }
    } else if (bid == 80) {
        float w0 = w0p[0];
#pragma unroll
        for (int it = 0; it < 64; ++it) {
            int e = t + it * 256;
            M[e] = adj[e] ? expf(-w0 * (float)tt[e]) : 0.f;
        }
    } else {
        float bv = bfp[0];
#pragma unroll
        for (int it = 0; it < 16; ++it) outv[t + it * 256] = bv;
    }
}

// ---------------------------------------------------------------------------
// next[b,i] = obs[b,i,:].w + sum_j act[b,j,i]*M[j,i]; also bf16 hi/lo split.
// 2 b per block, 256 threads: i-quad = t%32, j-group = (t/32)%4, b = t/128.
// ---------------------------------------------------------------------------
__global__ __launch_bounds__(256) void k_next(const float* __restrict__ obs,
                                              const float* __restrict__ act,
                                              const float* __restrict__ M,
                                              const float* __restrict__ w0p,
                                              float* __restrict__ outn,
                                              short* __restrict__ nxtH,
                                              short* __restrict__ nxtL) {
    __shared__ float P[2][4][128];
    __shared__ float wsh[16];
    int t = threadIdx.x;
    int b0 = blockIdx.x * 2;
    if (t < CC) wsh[t] = expf(-w0p[0] * (float)t);
    int i4 = t & 31, jg = (t >> 5) & 3, bo = t >> 7;
    const float* abase = act + (size_t)(b0 + bo) * ZZ * ZZ;
    float4 acc = make_float4(0.f, 0.f, 0.f, 0.f);
#pragma unroll 8
    for (int jj = 0; jj < 32; ++jj) {
        int j = jg * 32 + jj;
        float4 a = *(const float4*)&abase[j * ZZ + i4 * 4];
        float4 m = *(const float4*)&M[j * ZZ + i4 * 4];
        acc.x += a.x * m.x; acc.y += a.y * m.y; acc.z += a.z * m.z; acc.w += a.w * m.w;
    }
    *(float4*)&P[bo][jg][i4 * 4] = acc;
    __syncthreads();
    int i = t & 127, bo2 = t >> 7;
    int bb = b0 + bo2;
    float s = P[bo2][0][i] + P[bo2][1][i] + P[bo2][2][i] + P[bo2][3][i];
    const float* orow = obs + ((size_t)bb * ZZ + i) * CC;
#pragma unroll
    for (int c = 0; c < CC; ++c) s += orow[c] * wsh[c];
    outn[(size_t)bb * ZZ + i] = s;
    unsigned short h = f2bf(s);
    nxtH[bb * ZZ + i] = (short)h;
    nxtL[bb * ZZ + i] = (short)f2bf(s - bf2f(h));
}

// ---------------------------------------------------------------------------
// Split-bf16 MFMA GEMM: C = A @ Bt^T, A[M][K] hi/lo bf16, Bt[N][K] hi/lo bf16.
// Block: 64(M) x 128(N), BK=64, 128 threads = 2 waves (each 64x64, 4x4 frags
// of 16x16x32). XOR swizzle chunk^(row&7) -> conflict-free LDS.
// mode 0: out = relu(C+bias) split to OutH/OutL (bf16)
// mode 1: atomicAdd(OutDot[row], sum_col relu(C+bias)*Wf[col])
// ---------------------------------------------------------------------------
#define GBM 64
#define GBN 128
#define GBK 64

__global__ __launch_bounds__(128) void k_gemm(const short* __restrict__ Ah,
                                              const short* __restrict__ Al,
                                              const short* __restrict__ Bh,
                                              const short* __restrict__ Bl,
                                              const float* __restrict__ bias,
                                              int Kdim, int mode,
                                              short* __restrict__ OutH,
                                              short* __restrict__ OutL,
                                              const float* __restrict__ Wf,
                                              float* __restrict__ OutDot) {
    __shared__ __align__(16) short AsH[GBM * GBK], AsL[GBM * GBK];
    __shared__ __align__(16) short BsH[GBN * GBK], BsL[GBN * GBK];
    int t = threadIdx.x;
    int m0 = blockIdx.y * GBM, n0 = blockIdx.x * GBN;
    int lane = t & 63, wn = t >> 6;
    int l15 = lane & 15, l4 = lane >> 4;
    f32x4 acc[4][4] = {};

    for (int k0 = 0; k0 < Kdim; k0 += GBK) {
#pragma unroll
        for (int it = 0; it < 4; ++it) {
            int idx = t + it * 128; int row = idx >> 3, ch = idx & 7, cs = ch ^ (row & 7);
            *(int4*)&AsH[row * GBK + cs * 8] = *(const int4*)&Ah[(size_t)(m0 + row) * Kdim + k0 + ch * 8];
            *(int4*)&AsL[row * GBK + cs * 8] = *(const int4*)&Al[(size_t)(m0 + row) * Kdim + k0 + ch * 8];
        }
#pragma unroll
        for (int it = 0; it < 8; ++it) {
            int idx = t + it * 128; int row = idx >> 3, ch = idx & 7, cs = ch ^ (row & 7);
            *(int4*)&BsH[row * GBK + cs * 8] = *(const int4*)&Bh[(size_t)(n0 + row) * Kdim + k0 + ch * 8];
            *(int4*)&BsL[row * GBK + cs * 8] = *(const int4*)&Bl[(size_t)(n0 + row) * Kdim + k0 + ch * 8];
        }
        __syncthreads();
#pragma unroll
        for (int s = 0; s < 2; ++s) {
            short8 ah[4], al[4], bh[4], bl[4];
            int g = s * 4 + l4;
#pragma unroll
            for (int mf = 0; mf < 4; ++mf) {
                int row = mf * 16 + l15;
                int addr = row * GBK + ((g ^ (row & 7)) << 3);
                ah[mf] = *(const short8*)&AsH[addr];
                al[mf] = *(const short8*)&AsL[addr];
            }
#pragma unroll
            for (int nf = 0; nf < 4; ++nf) {
                int row = wn * 64 + nf * 16 + l15;
                int addr = row * GBK + ((g ^ (row & 7)) << 3);
                bh[nf] = *(const short8*)&BsH[addr];
                bl[nf] = *(const short8*)&BsL[addr];
            }
#pragma unroll
            for (int mf = 0; mf < 4; ++mf)
#pragma unroll
                for (int nf = 0; nf < 4; ++nf) {
                    acc[mf][nf] = __builtin_amdgcn_mfma_f32_16x16x32_bf16(ah[mf], bh[nf], acc[mf][nf], 0, 0, 0);
                    acc[mf][nf] = __builtin_amdgcn_mfma_f32_16x16x32_bf16(ah[mf], bl[nf], acc[mf][nf], 0, 0, 0);
                    acc[mf][nf] = __builtin_amdgcn_mfma_f32_16x16x32_bf16(al[mf], bh[nf], acc[mf][nf], 0, 0, 0);
                }
        }
        __syncthreads();
    }

    if (mode == 0) {
#pragma unroll
        for (int mf = 0; mf < 4; ++mf)
#pragma unroll
            for (int nf = 0; nf < 4; ++nf) {
                int col = n0 + wn * 64 + nf * 16 + l15;
                float bv = bias[col];
#pragma unroll
                for (int r = 0; r < 4; ++r) {
                    int row = m0 + mf * 16 + l4 * 4 + r;
                    float v = fmaxf(acc[mf][nf][r] + bv, 0.f);
                    unsigned short h = f2bf(v);
                    OutH[(size_t)row * HH + col] = (short)h;
                    OutL[(size_t)row * HH + col] = (short)f2bf(v - bf2f(h));
                }
            }
    } else {
        float bv[4], wv[4];
#pragma unroll
        for (int nf = 0; nf < 4; ++nf) {
            int col = n0 + wn * 64 + nf * 16 + l15;
            bv[nf] = bias[col];
            wv[nf] = Wf[col];
        }
#pragma unroll
        for (int mf = 0; mf < 4; ++mf)
#pragma unroll
            for (int r = 0; r < 4; ++r) {
                float p = 0.f;
#pragma unroll
                for (int nf = 0; nf < 4; ++nf)
                    p += fmaxf(acc[mf][nf][r] + bv[nf], 0.f) * wv[nf];
                p += __shfl_xor(p, 1);
                p += __shfl_xor(p, 2);
                p += __shfl_xor(p, 4);
                p += __shfl_xor(p, 8);
                if (l15 == 0) {
                    int row = m0 + mf * 16 + l4 * 4 + r;
                    atomicAdd(&OutDot[row], p);
                }
            }
    }
}

extern "C" void kernel_launch(void* const* d_in, const int* in_sizes, int n_in,
                              void* d_out, int out_size, void* d_ws, size_t ws_size,
                              hipStream_t stream) {
    const float* obs = (const float*)d_in[0];
    const float* act = (const float*)d_in[1];
    const float* w0  = (const float*)d_in[2];
    const float* W1  = (const float*)d_in[3];
    const float* b1  = (const float*)d_in[4];
    const float* W2  = (const float*)d_in[5];
    const float* b2  = (const float*)d_in[6];
    const float* Wf  = (const float*)d_in[7];
    const float* bf  = (const float*)d_in[8];
    const int* adj   = (const int*)d_in[9];
    const int* tt    = (const int*)d_in[10];

    float* out = (float*)d_out;           // [0:NB) symbolic_val, [NB:) next_state
    float* outn = out + NB;

    char* base = (char*)d_ws;
    float* M    = (float*)base;                         // 64 KB
    short* nxtH = (short*)(base + (1u << 16));          // 1 MB
    short* nxtL = (short*)(base + (1u << 16) + (1u << 20));
    char* p = base + (1u << 16) + (2u << 20);
    short* W1tH = (short*)p;               p += (size_t)HH * ZZ * 2;   // 128 KB
    short* W1tL = (short*)p;               p += (size_t)HH * ZZ * 2;
    short* W2tH = (short*)p;               p += (size_t)HH * HH * 2;   // 512 KB
    short* W2tL = (short*)p;               p += (size_t)HH * HH * 2;
    short* x1H  = (short*)p;               p += (size_t)NB * HH * 2;   // 4 MB
    short* x1L  = (short*)p;

    k_prep<<<82, 256, 0, stream>>>(W1, W2, adj, tt, w0, bf,
                                   W1tH, W1tL, W2tH, W2tL, M, out);
    k_next<<<NB / 2, 256, 0, stream>>>(obs, act, M, w0, outn, nxtH, nxtL);

    dim3 g(HH / GBN, NB / GBM);
    k_gemm<<<g, 128, 0, stream>>>(nxtH, nxtL, W1tH, W1tL, b1, ZZ, 0,
                                  x1H, x1L, (const float*)nullptr, (float*)nullptr);
    k_gemm<<<g, 128, 0, stream>>>(x1H, x1L, W2tH, W2tL, b2, HH, 1,
                                  (short*)nullptr, (short*)nullptr, Wf, out);
}

// Round 3
// 130.016 us; speedup vs baseline: 1.0670x; 1.0670x over previous
//
#include <hip/hip_runtime.h>
#include <math.h>

#define ZZ 128
#define CC 12
#define HH 512
#define NB 4096

typedef __attribute__((ext_vector_type(8))) short short8;
typedef __attribute__((ext_vector_type(4))) float f32x4;

__device__ __forceinline__ unsigned short f2bf(float x) {
    unsigned u = __builtin_bit_cast(unsigned, x);
    u += 0x7FFFu + ((u >> 16) & 1u);
    return (unsigned short)(u >> 16);
}
__device__ __forceinline__ float bf2f(unsigned short h) {
    unsigned u = ((unsigned)h) << 16;
    return __builtin_bit_cast(float, u);
}

// ---------------------------------------------------------------------------
// Prep: W1t/W2t transpose + bf16 hi/lo split; edge weights M; out[0:NB] = bf.
// ---------------------------------------------------------------------------
__global__ __launch_bounds__(256) void k_prep(const float* __restrict__ W1,
                                              const float* __restrict__ W2,
                                              const int* __restrict__ adj,
                                              const int* __restrict__ tt,
                                              const float* __restrict__ w0p,
                                              const float* __restrict__ bfp,
                                              short* __restrict__ W1tH, short* __restrict__ W1tL,
                                              short* __restrict__ W2tH, short* __restrict__ W2tL,
                                              float* __restrict__ M, float* __restrict__ outv) {
    int bid = blockIdx.x, t = threadIdx.x;
    if (bid < 80) {
        __shared__ float T[64][65];
        const float* src; short *dH, *dL; int k0, n0, Krows;
        if (bid < 64) { src = W2; dH = W2tH; dL = W2tL; Krows = HH; k0 = (bid & 7) * 64; n0 = (bid >> 3) * 64; }
        else { int b = bid - 64; src = W1; dH = W1tH; dL = W1tL; Krows = ZZ; k0 = (b & 1) * 64; n0 = (b >> 1) * 64; }
#pragma unroll
        for (int it = 0; it < 16; ++it) {
            int idx = t + it * 256; int r = idx >> 6, c = idx & 63;
            T[r][c] = src[(size_t)(k0 + r) * HH + n0 + c];
        }
        __syncthreads();
#pragma unroll
        for (int it = 0; it < 16; ++it) {
            int idx = t + it * 256; int nl = idx >> 6, kl = idx & 63;
            float v = T[kl][nl];
            unsigned short h = f2bf(v);
            float lo = v - bf2f(h);
            size_t o = (size_t)(n0 + nl) * Krows + k0 + kl;
            dH[o] = (short)h; dL[o] = (short)f2bf(lo);
        }
    } else if (bid == 80) {
        float w0 = w0p[0];
#pragma unroll
        for (int it = 0; it < 64; ++it) {
            int e = t + it * 256;
            M[e] = adj[e] ? expf(-w0 * (float)tt[e]) : 0.f;
        }
    } else {
        float bv = bfp[0];
#pragma unroll
        for (int it = 0; it < 16; ++it) outv[t + it * 256] = bv;
    }
}

// ---------------------------------------------------------------------------
// next[b,i] = obs[b,i,:].w + sum_j act[b,j,i]*M[j,i]; bf16 hi/lo side output.
// 2 b per block, 256 threads. obs staged via LDS transpose for coalescing.
// ---------------------------------------------------------------------------
__global__ __launch_bounds__(256) void k_next(const float* __restrict__ obs,
                                              const float* __restrict__ act,
                                              const float* __restrict__ M,
                                              const float* __restrict__ w0p,
                                              float* __restrict__ outn,
                                              short* __restrict__ nxtH,
                                              short* __restrict__ nxtL) {
    __shared__ float P[2][4][128];
    __shared__ float obsS[2][CC][128];
    __shared__ float wsh[16];
    int t = threadIdx.x;
    int b0 = blockIdx.x * 2;
    if (t < 16) wsh[t] = (t < CC) ? expf(-w0p[0] * (float)t) : 0.f;

    // cooperative coalesced obs load -> LDS transposed [bo][c][i]
    const float4* og = (const float4*)(obs + (size_t)b0 * ZZ * CC);
#pragma unroll
    for (int it = 0; it < 3; ++it) {
        int idx = t + it * 256;                 // [0, 768)
        float4 v = og[idx];
        int e = idx * 4;
        int bo = idx / 384;
        int rem = e - bo * 1536;
        int i = rem / CC;
        int c = rem - i * CC;                   // c in {0,4,8}
        obsS[bo][c + 0][i] = v.x;
        obsS[bo][c + 1][i] = v.y;
        obsS[bo][c + 2][i] = v.z;
        obsS[bo][c + 3][i] = v.w;
    }

    int i4 = t & 31, jg = (t >> 5) & 3, bo = t >> 7;
    const float* abase = act + (size_t)(b0 + bo) * ZZ * ZZ;
    float4 acc = make_float4(0.f, 0.f, 0.f, 0.f);
#pragma unroll 8
    for (int jj = 0; jj < 32; ++jj) {
        int j = jg * 32 + jj;
        float4 a = *(const float4*)&abase[j * ZZ + i4 * 4];
        float4 m = *(const float4*)&M[j * ZZ + i4 * 4];
        acc.x += a.x * m.x; acc.y += a.y * m.y; acc.z += a.z * m.z; acc.w += a.w * m.w;
    }
    *(float4*)&P[bo][jg][i4 * 4] = acc;
    __syncthreads();

    int i = t & 127, bo2 = t >> 7;
    int bb = b0 + bo2;
    float s = P[bo2][0][i] + P[bo2][1][i] + P[bo2][2][i] + P[bo2][3][i];
#pragma unroll
    for (int c = 0; c < CC; ++c) s += obsS[bo2][c][i] * wsh[c];
    outn[(size_t)bb * ZZ + i] = s;
    unsigned short h = f2bf(s);
    nxtH[bb * ZZ + i] = (short)h;
    nxtL[bb * ZZ + i] = (short)f2bf(s - bf2f(h));
}

// ---------------------------------------------------------------------------
// Split-bf16 MFMA GEMM: C = A @ Bt^T. 64x64 tile, BK=64, 256 thr = 4 waves,
// each wave a 32x32 quadrant (2x2 frags of 16x16x32). XOR-swizzled LDS.
// mode 0: Out = relu(C+bias) split to OutH/OutL
// mode 1: atomicAdd(OutDot[row], sum_col relu(C+bias)*Wf[col])
// ---------------------------------------------------------------------------
#define GBK 64

__global__ __launch_bounds__(256) void k_gemm(const short* __restrict__ Ah,
                                              const short* __restrict__ Al,
                                              const short* __restrict__ Bh,
                                              const short* __restrict__ Bl,
                                              const float* __restrict__ bias,
                                              int Kdim, int mode,
                                              short* __restrict__ OutH,
                                              short* __restrict__ OutL,
                                              const float* __restrict__ Wf,
                                              float* __restrict__ OutDot) {
    __shared__ __align__(16) short AsH[64 * GBK], AsL[64 * GBK];
    __shared__ __align__(16) short BsH[64 * GBK], BsL[64 * GBK];
    int t = threadIdx.x;
    int m0 = blockIdx.y * 64, n0 = blockIdx.x * 64;
    int lane = t & 63, w = t >> 6;
    int wm = w >> 1, wn = w & 1;
    int l15 = lane & 15, l4 = lane >> 4;
    f32x4 acc[2][2] = {};

    for (int k0 = 0; k0 < Kdim; k0 += GBK) {
#pragma unroll
        for (int it = 0; it < 2; ++it) {
            int idx = t + it * 256;             // [0,512): 64 rows x 8 chunks
            int row = idx >> 3, ch = idx & 7, cs = ch ^ (row & 7);
            *(int4*)&AsH[row * GBK + cs * 8] = *(const int4*)&Ah[(size_t)(m0 + row) * Kdim + k0 + ch * 8];
            *(int4*)&AsL[row * GBK + cs * 8] = *(const int4*)&Al[(size_t)(m0 + row) * Kdim + k0 + ch * 8];
            *(int4*)&BsH[row * GBK + cs * 8] = *(const int4*)&Bh[(size_t)(n0 + row) * Kdim + k0 + ch * 8];
            *(int4*)&BsL[row * GBK + cs * 8] = *(const int4*)&Bl[(size_t)(n0 + row) * Kdim + k0 + ch * 8];
        }
        __syncthreads();
#pragma unroll
        for (int s = 0; s < 2; ++s) {
            int g = s * 4 + l4;
            short8 ah[2], al[2], bh[2], bl[2];
#pragma unroll
            for (int mf = 0; mf < 2; ++mf) {
                int row = wm * 32 + mf * 16 + l15;
                int addr = row * GBK + ((g ^ (row & 7)) << 3);
                ah[mf] = *(const short8*)&AsH[addr];
                al[mf] = *(const short8*)&AsL[addr];
            }
#pragma unroll
            for (int nf = 0; nf < 2; ++nf) {
                int row = wn * 32 + nf * 16 + l15;
                int addr = row * GBK + ((g ^ (row & 7)) << 3);
                bh[nf] = *(const short8*)&BsH[addr];
                bl[nf] = *(const short8*)&BsL[addr];
            }
#pragma unroll
            for (int mf = 0; mf < 2; ++mf)
#pragma unroll
                for (int nf = 0; nf < 2; ++nf) {
                    acc[mf][nf] = __builtin_amdgcn_mfma_f32_16x16x32_bf16(ah[mf], bh[nf], acc[mf][nf], 0, 0, 0);
                    acc[mf][nf] = __builtin_amdgcn_mfma_f32_16x16x32_bf16(ah[mf], bl[nf], acc[mf][nf], 0, 0, 0);
                    acc[mf][nf] = __builtin_amdgcn_mfma_f32_16x16x32_bf16(al[mf], bh[nf], acc[mf][nf], 0, 0, 0);
                }
        }
        __syncthreads();
    }

    if (mode == 0) {
#pragma unroll
        for (int mf = 0; mf < 2; ++mf)
#pragma unroll
            for (int nf = 0; nf < 2; ++nf) {
                int col = n0 + wn * 32 + nf * 16 + l15;
                float bv = bias[col];
#pragma unroll
                for (int r = 0; r < 4; ++r) {
                    int row = m0 + wm * 32 + mf * 16 + l4 * 4 + r;
                    float v = fmaxf(acc[mf][nf][r] + bv, 0.f);
                    unsigned short h = f2bf(v);
                    OutH[(size_t)row * HH + col] = (short)h;
                    OutL[(size_t)row * HH + col] = (short)f2bf(v - bf2f(h));
                }
            }
    } else {
        float bv[2], wv[2];
#pragma unroll
        for (int nf = 0; nf < 2; ++nf) {
            int col = n0 + wn * 32 + nf * 16 + l15;
            bv[nf] = bias[col];
            wv[nf] = Wf[col];
        }
#pragma unroll
        for (int mf = 0; mf < 2; ++mf)
#pragma unroll
            for (int r = 0; r < 4; ++r) {
                float p = 0.f;
#pragma unroll
                for (int nf = 0; nf < 2; ++nf)
                    p += fmaxf(acc[mf][nf][r] + bv[nf], 0.f) * wv[nf];
                p += __shfl_xor(p, 1);
                p += __shfl_xor(p, 2);
                p += __shfl_xor(p, 4);
                p += __shfl_xor(p, 8);
                if (l15 == 0) {
                    int row = m0 + wm * 32 + mf * 16 + l4 * 4 + r;
                    atomicAdd(&OutDot[row], p);
                }
            }
    }
}

extern "C" void kernel_launch(void* const* d_in, const int* in_sizes, int n_in,
                              void* d_out, int out_size, void* d_ws, size_t ws_size,
                              hipStream_t stream) {
    const float* obs = (const float*)d_in[0];
    const float* act = (const float*)d_in[1];
    const float* w0  = (const float*)d_in[2];
    const float* W1  = (const float*)d_in[3];
    const float* b1  = (const float*)d_in[4];
    const float* W2  = (const float*)d_in[5];
    const float* b2  = (const float*)d_in[6];
    const float* Wf  = (const float*)d_in[7];
    const float* bf  = (const float*)d_in[8];
    const int* adj   = (const int*)d_in[9];
    const int* tt    = (const int*)d_in[10];

    float* out = (float*)d_out;           // [0:NB) symbolic_val, [NB:) next_state
    float* outn = out + NB;

    char* base = (char*)d_ws;
    float* M    = (float*)base;                         // 64 KB
    short* nxtH = (short*)(base + (1u << 16));          // 1 MB
    short* nxtL = (short*)(base + (1u << 16) + (1u << 20));
    char* p = base + (1u << 16) + (2u << 20);
    short* W1tH = (short*)p;               p += (size_t)HH * ZZ * 2;   // 128 KB
    short* W1tL = (short*)p;               p += (size_t)HH * ZZ * 2;
    short* W2tH = (short*)p;               p += (size_t)HH * HH * 2;   // 512 KB
    short* W2tL = (short*)p;               p += (size_t)HH * HH * 2;
    short* x1H  = (short*)p;               p += (size_t)NB * HH * 2;   // 4 MB
    short* x1L  = (short*)p;

    k_prep<<<82, 256, 0, stream>>>(W1, W2, adj, tt, w0, bf,
                                   W1tH, W1tL, W2tH, W2tL, M, out);
    k_next<<<NB / 2, 256, 0, stream>>>(obs, act, M, w0, outn, nxtH, nxtL);

    dim3 g(HH / 64, NB / 64);
    k_gemm<<<g, 256, 0, stream>>>(nxtH, nxtL, W1tH, W1tL, b1, ZZ, 0,
                                  x1H, x1L, (const float*)nullptr, (float*)nullptr);
    k_gemm<<<g, 256, 0, stream>>>(x1H, x1L, W2tH, W2tL, b2, HH, 1,
                                  (short*)nullptr, (short*)nullptr, Wf, out);
}